// Round 14
// baseline (6594.543 us; speedup 1.0000x reference)
//
#include <hip/hip_runtime.h>

#define B_ 16
#define V_ 2
#define D_ 768
#define NH_ 12
#define L_ 12
#define DH_ 64
#define N_ 49
#define S_ 256

__device__ __forceinline__ unsigned short f2bf(float f) {
  unsigned int u = __builtin_bit_cast(unsigned int, f);
  u += 0x7fffu + ((u >> 16) & 1u);
  return (unsigned short)(u >> 16);
}
__device__ __forceinline__ float bf2f(unsigned short h) {
  unsigned int u = ((unsigned int)h) << 16;
  return __builtin_bit_cast(float, u);
}
__device__ __forceinline__ float bflo(unsigned int w) {
  return __builtin_bit_cast(float, w << 16);
}
__device__ __forceinline__ float bfhi(unsigned int w) {
  return __builtin_bit_cast(float, w & 0xffff0000u);
}
__device__ __forceinline__ unsigned int packbf2(float a, float b) {
  return (unsigned int)f2bf(a) | ((unsigned int)f2bf(b) << 16);
}

using bf16x8 = __attribute__((ext_vector_type(8))) __bf16;
using u16x8  = __attribute__((ext_vector_type(8))) unsigned short;
using f32x4  = __attribute__((ext_vector_type(4))) float;

__device__ __forceinline__ void g2l16(const unsigned short* g, unsigned short* l) {
  __builtin_amdgcn_global_load_lds(
      (const __attribute__((address_space(1))) unsigned int*)g,
      (__attribute__((address_space(3))) unsigned int*)l, 16, 0, 0);
}

// ---------------------------------------------------------------- GEMM ----
// C = A(MxK bf16) @ W(NxK bf16)^T. Counted-vmcnt dbuf, XOR-swz LDS,
// bijective m-fastest XCD remap.
// EPI: 0=+bias, 1=+bias+gelu, 2=res+gate*(v+bias),
//   3=EPI2 + per-row {sum,sumsq} slot write, 4=LN-fold apply, 5=EPI4+gelu.
template <int BM, int BN, int BK, int EPI>
__global__ __launch_bounds__(256) void gemm_v7(
    const unsigned short* __restrict__ A, int lda,
    const unsigned short* __restrict__ W, int ldw,
    const float* __restrict__ bias,
    float* __restrict__ Cf, unsigned short* __restrict__ Cb, int ldc,
    const float* __restrict__ res, const float* __restrict__ gate,
    float* __restrict__ stats,
    int M, int N, int K)
{
  __shared__ unsigned short As[2][BM * BK];
  __shared__ unsigned short Bs[2][BN * BK];
  constexpr int FM = BM / 32, FN = BN / 32;
  constexpr int CPR = BK / 8;
  constexpr int LPS = (BM + BN) * BK / 2048;
  int m0, n0;
  {
    const int gx = gridDim.x;
    const int nwg = gx * gridDim.y;
    const int orig = blockIdx.y * gx + blockIdx.x;
    const int xcd = orig & 7, rem = orig >> 3;
    const int qq = nwg >> 3, rr = nwg & 7;
    const int wgid = (xcd < rr ? xcd * (qq + 1) : rr * (qq + 1) + (xcd - rr) * qq) + rem;
    m0 = (wgid % gx) * BM; n0 = (wgid / gx) * BN;
  }
  const int tid = threadIdx.x, lane = tid & 63, wid = tid >> 6;
  const int wr = wid >> 1, wc = wid & 1;
  const int fr = lane & 15, kq8 = lane >> 4;

  f32x4 acc[FM][FN];
#pragma unroll
  for (int mi = 0; mi < FM; ++mi)
#pragma unroll
    for (int ni = 0; ni < FN; ++ni) acc[mi][ni] = f32x4{0.f, 0.f, 0.f, 0.f};

  auto stage = [&](int buf, int k0) {
    const unsigned short* Ab = A + (size_t)m0 * lda + k0;
    const unsigned short* Bb = W + (size_t)n0 * ldw + k0;
#pragma unroll
    for (int ra = 0; ra < BM * BK / 2048; ++ra) {
      int c = ra * 256 + tid;
      int row = c / CPR, slot = c % CPR;
      g2l16(Ab + (size_t)row * lda + (slot ^ (row & 7)) * 8, &As[buf][c * 8]);
    }
#pragma unroll
    for (int rb = 0; rb < BN * BK / 2048; ++rb) {
      int c = rb * 256 + tid;
      int row = c / CPR, slot = c % CPR;
      g2l16(Bb + (size_t)row * ldw + (slot ^ (row & 7)) * 8, &Bs[buf][c * 8]);
    }
  };

  const int nt = K / BK;
  stage(0, 0);
  int cur = 0;
  for (int t = 0; t < nt; ++t) {
    if (t + 1 < nt) {
      stage(cur ^ 1, (t + 1) * BK);
      asm volatile("s_waitcnt vmcnt(%0)" :: "i"(LPS) : "memory");
    } else {
      asm volatile("s_waitcnt vmcnt(0)" ::: "memory");
    }
    __builtin_amdgcn_s_barrier();
#pragma unroll
    for (int ks = 0; ks < BK / 32; ++ks) {
      bf16x8 av[FM], bv[FN];
#pragma unroll
      for (int mi = 0; mi < FM; ++mi) {
        int row = wr * (BM / 2) + mi * 16 + fr;
        int idx = row * BK + (((ks * 4 + kq8) ^ (row & 7)) << 3);
        av[mi] = __builtin_bit_cast(bf16x8, *(const u16x8*)&As[cur][idx]);
      }
#pragma unroll
      for (int ni = 0; ni < FN; ++ni) {
        int row = wc * (BN / 2) + ni * 16 + fr;
        int idx = row * BK + (((ks * 4 + kq8) ^ (row & 7)) << 3);
        bv[ni] = __builtin_bit_cast(bf16x8, *(const u16x8*)&Bs[cur][idx]);
      }
#pragma unroll
      for (int mi = 0; mi < FM; ++mi)
#pragma unroll
        for (int ni = 0; ni < FN; ++ni)
          acc[mi][ni] = __builtin_amdgcn_mfma_f32_16x16x32_bf16(av[mi], bv[ni], acc[mi][ni], 0, 0, 0);
    }
    __builtin_amdgcn_s_barrier();
    cur ^= 1;
  }

  const int er = (lane >> 4) * 4, ec = lane & 15;
  float mu_[FM][4], rs_[FM][4];
  if constexpr (EPI >= 4) {
#pragma unroll
    for (int mi = 0; mi < FM; ++mi)
#pragma unroll
      for (int i = 0; i < 4; ++i) {
        int gr = m0 + wr * (BM / 2) + mi * 16 + er + i;
        float su = 0.f, sq = 0.f;
        if (gr < M) {
          const f32x4* sp = (const f32x4*)&stats[(size_t)gr * 48];
#pragma unroll
          for (int j = 0; j < 12; ++j) {
            f32x4 v4 = sp[j];
            su += v4.x + v4.z;
            sq += v4.y + v4.w;
          }
        }
        float mu = su * (1.0f / 768.0f);
        mu_[mi][i] = mu;
        rs_[mi][i] = rsqrtf(fmaxf(sq * (1.0f / 768.0f) - mu * mu, 0.f) + 1e-6f);
      }
  }
  float ssum[FM][4], sqsum[FM][4];
  if constexpr (EPI == 3) {
#pragma unroll
    for (int mi = 0; mi < FM; ++mi)
#pragma unroll
      for (int i = 0; i < 4; ++i) { ssum[mi][i] = 0.f; sqsum[mi][i] = 0.f; }
  }
#pragma unroll
  for (int mi = 0; mi < FM; ++mi)
#pragma unroll
    for (int ni = 0; ni < FN; ++ni) {
      int gc = n0 + wc * (BN / 2) + ni * 16 + ec;
      float bi = bias ? bias[gc] : 0.0f;
      float gg = gate ? gate[gc] : 1.0f;
#pragma unroll
      for (int i = 0; i < 4; ++i) {
        int gr = m0 + wr * (BM / 2) + mi * 16 + er + i;
        float v = acc[mi][ni][i];
        if constexpr (EPI == 0) {
          v += bi;
        } else if constexpr (EPI == 1) {
          v += bi;
          v = v / (1.0f + __expf(-1.59576912f * (v + 0.044715f * v * v * v)));
        } else if constexpr (EPI == 2 || EPI == 3) {
          v += bi;
          if (gr < M) v = res[(size_t)gr * ldc + gc] + gg * v;
        } else {
          v = (v - mu_[mi][i] * gg) * rs_[mi][i] + bi;
          if constexpr (EPI == 5)
            v = v / (1.0f + __expf(-1.59576912f * (v + 0.044715f * v * v * v)));
        }
        if (gr < M) {
          if (Cf) Cf[(size_t)gr * ldc + gc] = v;
          if (Cb) Cb[(size_t)gr * ldc + gc] = f2bf(v);
        }
        if constexpr (EPI == 3) { ssum[mi][i] += v; sqsum[mi][i] += v * v; }
      }
    }
  if constexpr (EPI == 3) {
    const int nb = n0 >> 6;
#pragma unroll
    for (int mi = 0; mi < FM; ++mi)
#pragma unroll
      for (int i = 0; i < 4; ++i) {
        float s = ssum[mi][i], q = sqsum[mi][i];
#pragma unroll
        for (int off = 1; off <= 8; off <<= 1) {
          s += __shfl_xor(s, off);
          q += __shfl_xor(q, off);
        }
        int gr = m0 + wr * (BM / 2) + mi * 16 + er + i;
        if ((lane & 15) == 0 && gr < M) {
          stats[(size_t)gr * 48 + (nb * 2 + wc) * 2]     = s;
          stats[(size_t)gr * 48 + (nb * 2 + wc) * 2 + 1] = q;
        }
      }
  }
}

// ------------------------------------------------------ MFMA attention ----
template <int LKPAD>
__global__ __launch_bounds__(256) void attn_mfma(
    const unsigned short* __restrict__ Q, int ldq, int qoff, int Lq,
    const unsigned short* __restrict__ KV, int ldkv, int koff, int voff, int Lk,
    const float* __restrict__ cq, const float* __restrict__ sq, int rbq,
    const float* __restrict__ ck, const float* __restrict__ sk, int rbk,
    unsigned short* __restrict__ Out)
{
  constexpr int NT = LKPAD / 16;
  constexpr int NKS = LKPAD / 32;
  __shared__ unsigned short Kb[LKPAD * 64];
  __shared__ unsigned short Vt[64 * LKPAD];
  __shared__ unsigned short Qs[4][16 * 64];
  __shared__ unsigned short Pl[4][16 * LKPAD];
  const int b = blockIdx.x / NH_, h = blockIdx.x - b * NH_;
  const int tid = threadIdx.x, lane = tid & 63, wid = tid >> 6;

  for (int idx = tid; idx < LKPAD * 32; idx += 256) {
    int t = idx >> 5, m = idx & 31;
    int d = 2 * m;
    int ksl = (t << 6) + (((m >> 2) ^ (t & 7)) << 3) + ((m & 3) << 1);
    int vs0 = d * LKPAD + (((t >> 3) ^ (d & 7)) << 3) + (t & 7);
    int vs1 = (d + 1) * LKPAD + (((t >> 3) ^ ((d + 1) & 7)) << 3) + (t & 7);
    if (t < Lk) {
      size_t rowb = ((size_t)b * Lk + t) * ldkv;
      unsigned int kw = *(const unsigned int*)(KV + rowb + koff + h * DH_ + d);
      unsigned int vw = *(const unsigned int*)(KV + rowb + voff + h * DH_ + d);
      float k1 = bflo(kw), k2 = bfhi(kw);
      size_t ri = (size_t)b * rbk + (size_t)t * 32 + m;
      float c = ck[ri], s = sk[ri];
      *(unsigned int*)&Kb[ksl] = packbf2((k1 * c - k2 * s) * 0.125f, (k1 * s + k2 * c) * 0.125f);
      Vt[vs0] = (unsigned short)(vw & 0xffff);
      Vt[vs1] = (unsigned short)(vw >> 16);
    } else {
      *(unsigned int*)&Kb[ksl] = 0;
      Vt[vs0] = 0; Vt[vs1] = 0;
    }
  }
  const int qbase = blockIdx.y * 64 + wid * 16;
  for (int idx = lane; idx < 16 * 32; idx += 64) {
    int r = idx >> 5, m = idx & 31;
    int gq = qbase + r;
    unsigned int qr = 0;
    if (gq < Lq) {
      unsigned int qw = *(const unsigned int*)(Q + ((size_t)b * Lq + gq) * ldq + qoff + h * DH_ + 2 * m);
      float q1 = bflo(qw), q2 = bfhi(qw);
      size_t ri = (size_t)b * rbq + (size_t)gq * 32 + m;
      float c = cq[ri], s = sq[ri];
      qr = packbf2(q1 * c - q2 * s, q1 * s + q2 * c);
    }
    *(unsigned int*)&Qs[wid][(r << 6) + (((m >> 2) ^ (r & 7)) << 3) + ((m & 3) << 1)] = qr;
  }
  __syncthreads();

  const int fr = lane & 15, g = lane >> 4;
  bf16x8 qa[2];
#pragma unroll
  for (int ks = 0; ks < 2; ++ks)
    qa[ks] = __builtin_bit_cast(bf16x8,
        *(const u16x8*)&Qs[wid][(fr << 6) + ((((ks << 2) + g) ^ (fr & 7)) << 3)]);

  f32x4 sv[NT];
  __builtin_amdgcn_s_setprio(1);
#pragma unroll
  for (int t = 0; t < NT; ++t) {
    int key = (t << 4) + fr;
    f32x4 a = {0.f, 0.f, 0.f, 0.f};
#pragma unroll
    for (int ks = 0; ks < 2; ++ks) {
      bf16x8 kb = __builtin_bit_cast(bf16x8,
          *(const u16x8*)&Kb[(key << 6) + ((((ks << 2) + g) ^ (key & 7)) << 3)]);
      a = __builtin_amdgcn_mfma_f32_16x16x32_bf16(qa[ks], kb, a, 0, 0, 0);
    }
    sv[t] = a;
  }
  __builtin_amdgcn_s_setprio(0);
#pragma unroll
  for (int t = 0; t < NT; ++t) {
    int key = (t << 4) + fr;
    if (key >= Lk) sv[t] = f32x4{-1e30f, -1e30f, -1e30f, -1e30f};
  }
  f32x4 mx = sv[0];
#pragma unroll
  for (int t = 1; t < NT; ++t)
#pragma unroll
    for (int i = 0; i < 4; ++i) mx[i] = fmaxf(mx[i], sv[t][i]);
#pragma unroll
  for (int off = 1; off <= 8; off <<= 1)
#pragma unroll
    for (int i = 0; i < 4; ++i) mx[i] = fmaxf(mx[i], __shfl_xor(mx[i], off));
  f32x4 sm = {0.f, 0.f, 0.f, 0.f};
#pragma unroll
  for (int t = 0; t < NT; ++t)
#pragma unroll
    for (int i = 0; i < 4; ++i) {
      float e = __expf(sv[t][i] - mx[i]);
      sv[t][i] = e;
      sm[i] += e;
    }
#pragma unroll
  for (int off = 1; off <= 8; off <<= 1)
#pragma unroll
    for (int i = 0; i < 4; ++i) sm[i] += __shfl_xor(sm[i], off);
  f32x4 inv;
#pragma unroll
  for (int i = 0; i < 4; ++i) inv[i] = 1.0f / sm[i];
#pragma unroll
  for (int t = 0; t < NT; ++t) {
    int key = (t << 4) + fr;
    int chunk = key >> 3;
#pragma unroll
    for (int i = 0; i < 4; ++i) {
      int row = (g << 2) + i;
      Pl[wid][row * LKPAD + ((chunk ^ (row & 7)) << 3) + (key & 7)] = f2bf(sv[t][i]);
    }
  }
  f32x4 oacc[4];
#pragma unroll
  for (int n = 0; n < 4; ++n) oacc[n] = f32x4{0.f, 0.f, 0.f, 0.f};
  __builtin_amdgcn_s_setprio(1);
#pragma unroll
  for (int ks = 0; ks < NKS; ++ks) {
    int chunk = (ks << 2) + g;
    bf16x8 pa = __builtin_bit_cast(bf16x8,
        *(const u16x8*)&Pl[wid][fr * LKPAD + ((chunk ^ (fr & 7)) << 3)]);
#pragma unroll
    for (int n = 0; n < 4; ++n) {
      int drow = (n << 4) + fr;
      bf16x8 vb = __builtin_bit_cast(bf16x8,
          *(const u16x8*)&Vt[drow * LKPAD + ((chunk ^ (drow & 7)) << 3)]);
      oacc[n] = __builtin_amdgcn_mfma_f32_16x16x32_bf16(pa, vb, oacc[n], 0, 0, 0);
    }
  }
  __builtin_amdgcn_s_setprio(0);
#pragma unroll
  for (int n = 0; n < 4; ++n)
#pragma unroll
    for (int i = 0; i < 4; ++i) {
      int gq = qbase + (g << 2) + i;
      if (gq < Lq)
        Out[((size_t)b * Lq + gq) * D_ + h * DH_ + (n << 4) + fr] = f2bf(oacc[n][i] * inv[i]);
    }
}

// ------------------------------------------------------ weight convert ----
struct CvtA {
  const float* s[11];
  unsigned short* d[11];
  const float* g[11];
  unsigned int lsrc[11];
  unsigned int lstride[11];
  int blkEnd[11];
};
__global__ __launch_bounds__(256) void cvt_multi_k(CvtA c) {
  int bid = blockIdx.x;
  int seg = 0;
#pragma unroll
  for (int i = 0; i < 10; ++i) seg += (bid >= c.blkEnd[i]) ? 1 : 0;
  unsigned int e = (unsigned int)(bid - (seg ? c.blkEnd[seg - 1] : 0)) * 2048u
                   + (unsigned int)threadIdx.x * 8u;
  unsigned int l = e / c.lsrc[seg], r = e - l * c.lsrc[seg];
  const float* s = c.s[seg] + e;
  unsigned short* d = c.d[seg] + (size_t)l * c.lstride[seg] + r;
  f32x4 a = *(const f32x4*)s, b2 = *(const f32x4*)(s + 4);
  const float* gp = c.g[seg];
  if (gp) {
    unsigned int k = e % 768u;
    const float* gpp = gp + (size_t)l * 768u + k;
    f32x4 ga = *(const f32x4*)gpp, gb = *(const f32x4*)(gpp + 4);
    a.x *= ga.x; a.y *= ga.y; a.z *= ga.z; a.w *= ga.w;
    b2.x *= gb.x; b2.y *= gb.y; b2.z *= gb.z; b2.w *= gb.w;
  }
  u16x8 o;
  o[0] = f2bf(a.x); o[1] = f2bf(a.y); o[2] = f2bf(a.z); o[3] = f2bf(a.w);
  o[4] = f2bf(b2.x); o[5] = f2bf(b2.y); o[6] = f2bf(b2.z); o[7] = f2bf(b2.w);
  *(u16x8*)d = o;
}

// LN-fold vectors: c_n = sum_k gamma_k W[n,k]; b_n = bias_n + sum_k beta_k W[n,k]
__global__ __launch_bounds__(256) void foldprep_k(
    const float* __restrict__ qkvw, const float* __restrict__ qkvb,
    const float* __restrict__ g1, const float* __restrict__ b1,
    const float* __restrict__ m1w, const float* __restrict__ m1b,
    const float* __restrict__ g2, const float* __restrict__ b2,
    float* __restrict__ cq, float* __restrict__ bq,
    float* __restrict__ cm, float* __restrict__ bm)
{
  int row = blockIdx.x * 4 + (threadIdx.x >> 6);
  int lane = threadIdx.x & 63;
  const int QT = L_ * 2304;
  const float *wrow, *gv, *bv;
  float bb; float *co, *bo; int oi;
  if (row < QT) {
    int l = row / 2304, n = row - l * 2304;
    wrow = qkvw + ((size_t)l * 2304 + n) * 768;
    gv = g1 + l * 768; bv = b1 + l * 768;
    bb = qkvb[row]; co = cq; bo = bq; oi = row;
  } else {
    int r2 = row - QT;
    int l = r2 / 3072, n = r2 - l * 3072;
    wrow = m1w + ((size_t)l * 3072 + n) * 768;
    gv = g2 + l * 768; bv = b2 + l * 768;
    bb = m1b[r2]; co = cm; bo = bm; oi = r2;
  }
  float cs = 0.f, bs = 0.f;
#pragma unroll
  for (int j = 0; j < 12; ++j) {
    float w = wrow[lane + 64 * j];
    cs += w * gv[lane + 64 * j];
    bs += w * bv[lane + 64 * j];
  }
  for (int o = 32; o; o >>= 1) { cs += __shfl_xor(cs, o); bs += __shfl_xor(bs, o); }
  if (lane == 0) { co[oi] = cs; bo[oi] = bb + bs; }
}

__global__ void cvt_patch_k(const float* __restrict__ s, unsigned short* __restrict__ d) {
  int i = blockIdx.x * 256 + threadIdx.x;
  if (i >= 768 * 768) return;
  int r = i / 768, col = i - r * 768;
  d[i] = f2bf(col < 588 ? s[r * 588 + col] : 0.0f);
}

// merged: scene rope table + fused biases (fb, fb2)
__global__ void prep_misc_k(float* __restrict__ c, float* __restrict__ s,
                            const float* __restrict__ wqb, const float* __restrict__ rkvb,
                            const float* __restrict__ wkvb, const float* __restrict__ rqb,
                            float* __restrict__ fb, float* __restrict__ fb2) {
  int idx = blockIdx.x * 256 + threadIdx.x;
  if (idx < S_ * 32) {
    int t = idx >> 5, m = idx & 31;
    int i = t >> 4, j = t & 15;
    float xx = -1.0f + 2.0f * j / 15.0f;
    float yy = -1.0f + 2.0f * i / 15.0f;
    float coord = (m < 16) ? xx : yy;
    float per = powf(100.0f, (float)(m & 15) / 16.0f);
    float ang = coord / per;
    c[idx] = cosf(ang); s[idx] = sinf(ang);
  }
  if (idx < L_ * 2304) {
    int l = idx / 2304, cc = idx - l * 2304;
    fb[idx]  = (cc < 768) ? wqb[l * 768 + cc] : rkvb[l * 1536 + (cc - 768)];
    fb2[idx] = (cc < 1536) ? wkvb[l * 1536 + cc] : rqb[((l + 1) % L_) * 768 + (cc - 1536)];
  }
}

// --------------------------------------------------------------- misc ----
__global__ void init_scene_k(const float* __restrict__ tok, float* __restrict__ sf,
                             unsigned short* __restrict__ sb, int total) {
  int i = blockIdx.x * 256 + threadIdx.x;
  if (i < total) {
    float v = tok[i % (S_ * D_)];
    sf[i] = v; sb[i] = f2bf(v);
  }
}

// im2col + local rope table in one kernel
__global__ void im2col_k(unsigned short* __restrict__ xb, const float* __restrict__ img,
                         const float* __restrict__ ctr, const float* __restrict__ scl,
                         float* __restrict__ lc, float* __restrict__ ls) {
  int idx = blockIdx.x * 256 + threadIdx.x;
  if (idx >= 784 * 768) return;
  int row = idx / 768, col = idx - row * 768;
  float val = 0.0f;
  if (col < 588) {
    int b = row / 49, pch = row - b * 49;
    int c = col / 196, rr = col - c * 196;
    int i = rr / 14, j = rr - i * 14;
    int py = pch / 7, px = pch - py * 7;
    int gyi = py * 14 + i, gxi = px * 14 + j;
    float cx = ctr[b * 2], cy = ctr[b * 2 + 1], sc = scl[b];
    float gy = cy + sc * (-1.0f + 2.0f * gyi / 97.0f);
    float gx = cx + sc * (-1.0f + 2.0f * gxi / 97.0f);
    float pyi = (gy + 1.0f) * 0.5f * 223.0f;
    float pxi = (gx + 1.0f) * 0.5f * 223.0f;
    float y0f = fminf(fmaxf(floorf(pyi), 0.0f), 222.0f);
    float x0f = fminf(fmaxf(floorf(pxi), 0.0f), 222.0f);
    int y0 = (int)y0f, x0 = (int)x0f;
    float wy = fminf(fmaxf(pyi - y0f, 0.0f), 1.0f);
    float wx = fminf(fmaxf(pxi - x0f, 0.0f), 1.0f);
    const float* base = img + (size_t)(b * 3 + c) * 224 * 224;
    float v00 = base[y0 * 224 + x0],       v01 = base[y0 * 224 + x0 + 1];
    float v10 = base[(y0 + 1) * 224 + x0], v11 = base[(y0 + 1) * 224 + x0 + 1];
    val = (v00 * (1.0f - wy) + v10 * wy) * (1.0f - wx) + (v01 * (1.0f - wy) + v11 * wy) * wx;
  }
  xb[idx] = f2bf(val);
  if (idx < B_ * N_ * 32) {
    int b = idx / (N_ * 32);
    int r = idx - b * (N_ * 32);
    int pch = r >> 5, m = r & 31;
    int py = pch / 7, px = pch - py * 7;
    float cx = ctr[b * 2], cy = ctr[b * 2 + 1], sc = scl[b];
    float gx = cx + sc * ((px - 3.0f) / 3.0f);
    float gy = cy + sc * ((py - 3.0f) / 3.0f);
    float coord = (m < 16) ? gx : gy;
    float per = powf(100.0f, (float)(m & 15) / 16.0f);
    float ang = coord / per;
    lc[idx] = cosf(ang); ls[idx] = sinf(ang);
  }
}

// -------------------------------------------------------------- launch ----
extern "C" void kernel_launch(void* const* d_in, const int* in_sizes, int n_in,
                              void* d_out, int out_size, void* d_ws, size_t ws_size,
                              hipStream_t stream) {
  const float* images    = (const float*)d_in[0];
  const float* centers   = (const float*)d_in[1];
  const float* scales    = (const float*)d_in[2];
  const float* patch_w   = (const float*)d_in[3];
  const float* patch_b   = (const float*)d_in[4];
  const float* scene_tok = (const float*)d_in[5];
  const float* ln1_w = (const float*)d_in[6];
  const float* ln1_b = (const float*)d_in[7];
  const float* ln2_w = (const float*)d_in[8];
  const float* ln2_b = (const float*)d_in[9];
  const float* qkv_w = (const float*)d_in[10];
  const float* qkv_b = (const float*)d_in[11];
  const float* ao_w  = (const float*)d_in[12];
  const float* ao_b  = (const float*)d_in[13];
  const float* m1_w  = (const float*)d_in[14];
  const float* m1_b  = (const float*)d_in[15];
  const float* m2_w  = (const float*)d_in[16];
  const float* m2_b  = (const float*)d_in[17];
  const float* rq_w  = (const float*)d_in[18];
  const float* rq_b  = (const float*)d_in[19];
  const float* rkv_w = (const float*)d_in[20];
  const float* rkv_b = (const float*)d_in[21];
  const float* ro_w  = (const float*)d_in[22];
  const float* ro_b  = (const float*)d_in[23];
  const float* rgate = (const float*)d_in[24];
  const float* wq_w  = (const float*)d_in[25];
  const float* wq_b  = (const float*)d_in[26];
  const float* wkv_w = (const float*)d_in[27];
  const float* wkv_b = (const float*)d_in[28];
  const float* wo_w  = (const float*)d_in[29];
  const float* wo_b  = (const float*)d_in[30];
  const float* wgate = (const float*)d_in[31];

  float* scene_f = (float*)d_out;

  char* p = (char*)d_ws;
  auto alloc = [&](size_t bytes) { char* r = p; p += (bytes + 255) & ~(size_t)255; return (void*)r; };
  unsigned short* scene_bf = (unsigned short*)alloc((size_t)4096 * 768 * 2);
  float*          local_f  = (float*)alloc((size_t)784 * 768 * 4);
  unsigned short* local_bf = (unsigned short*)alloc((size_t)896 * 768 * 2);
  unsigned short* q_r_bf   = (unsigned short*)alloc((size_t)896 * 768 * 2);
  unsigned short* qrkv_bf  = (unsigned short*)alloc((size_t)4096 * 2304 * 2);
  unsigned short* kv_bf    = (unsigned short*)alloc((size_t)896 * 2304 * 2);
  unsigned short* kvq_bf   = (unsigned short*)alloc((size_t)896 * 2304 * 2);
  unsigned short* act_bf   = (unsigned short*)alloc((size_t)4096 * 768 * 2);
  unsigned short* x_bf     = (unsigned short*)alloc((size_t)896 * 768 * 2);
  float* sc_cos = (float*)alloc((size_t)S_ * 32 * 4);
  float* sc_sin = (float*)alloc((size_t)S_ * 32 * 4);
  float* l_cos  = (float*)alloc((size_t)B_ * N_ * 32 * 4);
  float* l_sin  = (float*)alloc((size_t)B_ * N_ * 32 * 4);
  unsigned short* patch_wbf = (unsigned short*)alloc((size_t)768 * 768 * 2);
  float*          fb        = (float*)alloc((size_t)L_ * 2304 * 4);
  float*          fb2       = (float*)alloc((size_t)L_ * 2304 * 4);
  float*          cq_v      = (float*)alloc((size_t)L_ * 2304 * 4);
  float*          bq_v      = (float*)alloc((size_t)L_ * 2304 * 4);
  float*          cm_v      = (float*)alloc((size_t)L_ * 3072 * 4);
  float*          bm_v      = (float*)alloc((size_t)L_ * 3072 * 4);
  float*          stats1    = (float*)alloc((size_t)832 * 48 * 4);
  float*          stats2    = (float*)alloc((size_t)832 * 48 * 4);

  static const size_t REGSZ[9] = {589824, 1769472, 589824, 1769472, 589824,
                                  2359296, 2359296, 1769472, 589824};
  struct SegDef { const float* src; int reg; unsigned off; unsigned lsrc; int nl; const float* gma; };
  const SegDef SEGS[11] = {
    {rq_w,            0, 0,       589824,  L_,     nullptr},
    {wq_w,            1, 0,       589824,  L_,     nullptr},
    {rkv_w,           1, 589824,  1179648, L_,     nullptr},
    {ro_w,            2, 0,       589824,  L_,     nullptr},
    {qkv_w,           3, 0,       1769472, L_,     ln1_w},
    {ao_w,            4, 0,       589824,  L_,     nullptr},
    {m1_w,            5, 0,       2359296, L_,     ln2_w},
    {m2_w,            6, 0,       2359296, L_,     nullptr},
    {wkv_w,           7, 0,       1179648, L_,     nullptr},
    {rq_w + 589824,   7, 1179648, 589824,  L_ - 1, nullptr},
    {wo_w,            8, 0,       589824,  L_,     nullptr},
  };
  size_t regBase[9];
  size_t perLayer = 0;
  {
    size_t cur = 0;
    for (int i = 0; i < 9; ++i) { regBase[i] = cur; cur += REGSZ[i] * L_; perLayer += REGSZ[i]; }
  }
  const size_t allElems = perLayer * L_;
  size_t usedBytes = (size_t)(p - (char*)d_ws);
  bool preconv = ws_size >= usedBytes + allElems * 2 + 4096;
  unsigned short* wbf = (unsigned short*)alloc((preconv ? allElems : perLayer) * 2);

  {
    int total = B_ * S_ * D_;
    init_scene_k<<<(total + 255) / 256, 256, 0, stream>>>(scene_tok, scene_f, scene_bf, total);
    prep_misc_k<<<(L_ * 2304 + 255) / 256, 256, 0, stream>>>(
        sc_cos, sc_sin, wq_b, rkv_b, wkv_b, rq_b, fb, fb2);
    cvt_patch_k<<<(768 * 768 + 255) / 256, 256, 0, stream>>>(patch_w, patch_wbf);
    foldprep_k<<<(L_ * (2304 + 3072)) / 4, 256, 0, stream>>>(
        qkv_w, qkv_b, ln1_w, ln1_b, m1_w, m1_b, ln2_w, ln2_b, cq_v, bq_v, cm_v, bm_v);
    if (preconv) {
      CvtA cv;
      int blk = 0;
      for (int i = 0; i < 11; ++i) {
        cv.s[i] = SEGS[i].src;
        cv.d[i] = wbf + regBase[SEGS[i].reg] + SEGS[i].off;
        cv.g[i] = SEGS[i].gma;
        cv.lsrc[i] = SEGS[i].lsrc;
        cv.lstride[i] = (unsigned)REGSZ[SEGS[i].reg];
        blk += (int)((size_t)SEGS[i].lsrc * SEGS[i].nl / 2048);
        cv.blkEnd[i] = blk;
      }
      cvt_multi_k<<<blk, 256, 0, stream>>>(cv);
    }
  }

  for (int vp = 0; vp < V_; ++vp) {
    const float* ctr = centers + (size_t)vp * B_ * 2;
    const float* scl = scales + (size_t)vp * B_;
    im2col_k<<<(784 * 768 + 255) / 256, 256, 0, stream>>>(x_bf, images, ctr, scl, l_cos, l_sin);
    gemm_v7<64, 64, 128, 0><<<dim3(13, 12), 256, 0, stream>>>(
        x_bf, 768, patch_wbf, 768, patch_b, local_f, local_bf, 768,
        nullptr, nullptr, nullptr, 784, 768, 768);

    for (int l = 0; l < L_; ++l) {
      const unsigned short* wR[9];
      if (preconv) {
        for (int rg = 0; rg < 9; ++rg)
          wR[rg] = wbf + regBase[rg] + (size_t)l * REGSZ[rg];
      } else {
        CvtA cv;
        int blk = 0;
        size_t cur = 0;
        size_t rb[9];
        for (int rg = 0; rg < 9; ++rg) { rb[rg] = cur; cur += REGSZ[rg]; wR[rg] = wbf + rb[rg]; }
        for (int i = 0; i < 11; ++i) {
          size_t srcl = (i == 9) ? (size_t)((l + 1) % L_) : (size_t)l;
          cv.s[i] = (i == 9 ? rq_w : SEGS[i].src) + srcl * SEGS[i].lsrc;
          cv.d[i] = wbf + rb[SEGS[i].reg] + SEGS[i].off;
          cv.g[i] = SEGS[i].gma ? SEGS[i].gma + srcl * 768 : nullptr;
          cv.lsrc[i] = SEGS[i].lsrc;
          cv.lstride[i] = (unsigned)REGSZ[SEGS[i].reg];
          blk += (int)(SEGS[i].lsrc / 2048);
          cv.blkEnd[i] = blk;
        }
        cvt_multi_k<<<blk, 256, 0, stream>>>(cv);
      }

      // ---- qrkv (scene): wq|rkv fused — BK=128 this round (12->6 K-steps;
      // 576 blocks > 256 CUs so 1 blk/CU costs no coverage) ----
      gemm_v7<128, 128, 128, 0><<<dim3(32, 18), 256, 0, stream>>>(
          scene_bf, 768, wR[1], 768, fb + (size_t)l * 2304,
          nullptr, qrkv_bf, 2304, nullptr, nullptr, nullptr, 4096, 2304, 768);
      if (l == 0)
        gemm_v7<64, 64, 128, 0><<<dim3(13, 12), 256, 0, stream>>>(
            local_bf, 768, wR[0], 768, rq_b + l * 768,
            nullptr, q_r_bf, 768, nullptr, nullptr, nullptr, 784, 768, 768);
      // ---- read cross ----
      if (l == 0)
        attn_mfma<256><<<dim3(B_ * NH_, 1), 256, 0, stream>>>(q_r_bf, 768, 0, 49,
            qrkv_bf, 2304, 768, 1536, 256, l_cos, l_sin, N_ * 32, sc_cos, sc_sin, 0, act_bf);
      else
        attn_mfma<256><<<dim3(B_ * NH_, 1), 256, 0, stream>>>(kvq_bf, 2304, 1536, 49,
            qrkv_bf, 2304, 768, 1536, 256, l_cos, l_sin, N_ * 32, sc_cos, sc_sin, 0, act_bf);
      // ro: residual + ln1 stats (slots)
      gemm_v7<64, 64, 128, 3><<<dim3(13, 12), 256, 0, stream>>>(
          act_bf, 768, wR[2], 768, ro_b + l * 768,
          local_f, local_bf, 768, local_f, rgate + l * 768, stats1, 784, 768, 768);
      // qkv: LN1 folded
      gemm_v7<64, 64, 128, 4><<<dim3(13, 36), 256, 0, stream>>>(
          local_bf, 768, wR[3], 768, bq_v + (size_t)l * 2304,
          nullptr, kv_bf, 2304, nullptr, cq_v + (size_t)l * 2304, stats1, 784, 2304, 768);
      attn_mfma<64><<<dim3(B_ * NH_, 1), 256, 0, stream>>>(kv_bf, 2304, 0, 49,
          kv_bf, 2304, 768, 1536, 49, l_cos, l_sin, N_ * 32, l_cos, l_sin, N_ * 32, act_bf);
      // ao: residual + ln2 stats
      gemm_v7<64, 64, 128, 3><<<dim3(13, 12), 256, 0, stream>>>(
          act_bf, 768, wR[4], 768, ao_b + l * 768,
          local_f, local_bf, 768, local_f, nullptr, stats2, 784, 768, 768);
      // m1: LN2 folded + gelu
      gemm_v7<64, 64, 128, 5><<<dim3(13, 48), 256, 0, stream>>>(
          local_bf, 768, wR[5], 768, bm_v + (size_t)l * 3072,
          nullptr, act_bf, 3072, nullptr, cm_v + (size_t)l * 3072, stats2, 784, 3072, 768);
      gemm_v7<64, 64, 128, 2><<<dim3(13, 12), 256, 0, stream>>>(
          act_bf, 3072, wR[6], 3072, m2_b + l * 768,
          local_f, local_bf, 768, local_f, nullptr, nullptr, 784, 768, 3072);
      // ---- wkv + rq(l+1) merged ----
      gemm_v7<64, 64, 128, 0><<<dim3(13, 36), 256, 0, stream>>>(
          local_bf, 768, wR[7], 768, fb2 + (size_t)l * 2304,
          nullptr, kvq_bf, 2304, nullptr, nullptr, nullptr, 784, 2304, 768);
      // ---- write cross ----
      attn_mfma<64><<<dim3(B_ * NH_, 4), 256, 0, stream>>>(qrkv_bf, 2304, 0, 256,
          kvq_bf, 2304, 0, 768, 49, sc_cos, sc_sin, 0, l_cos, l_sin, N_ * 32, act_bf);
      gemm_v7<128, 64, 64, 2><<<dim3(32, 12), 256, 0, stream>>>(
          act_bf, 768, wR[8], 768, wo_b + l * 768,
          scene_f, scene_bf, 768, scene_f, wgate + l * 768, nullptr, 4096, 768, 768);
    }
  }
}

// Round 15
// 6115.631 us; speedup vs baseline: 1.0783x; 1.0783x over previous
//
#include <hip/hip_runtime.h>

#define B_ 16
#define V_ 2
#define D_ 768
#define NH_ 12
#define L_ 12
#define DH_ 64
#define N_ 49
#define S_ 256

__device__ __forceinline__ unsigned short f2bf(float f) {
  unsigned int u = __builtin_bit_cast(unsigned int, f);
  u += 0x7fffu + ((u >> 16) & 1u);
  return (unsigned short)(u >> 16);
}
__device__ __forceinline__ float bf2f(unsigned short h) {
  unsigned int u = ((unsigned int)h) << 16;
  return __builtin_bit_cast(float, u);
}
__device__ __forceinline__ float bflo(unsigned int w) {
  return __builtin_bit_cast(float, w << 16);
}
__device__ __forceinline__ float bfhi(unsigned int w) {
  return __builtin_bit_cast(float, w & 0xffff0000u);
}
__device__ __forceinline__ unsigned int packbf2(float a, float b) {
  return (unsigned int)f2bf(a) | ((unsigned int)f2bf(b) << 16);
}

using bf16x8 = __attribute__((ext_vector_type(8))) __bf16;
using u16x8  = __attribute__((ext_vector_type(8))) unsigned short;
using f32x4  = __attribute__((ext_vector_type(4))) float;

__device__ __forceinline__ void g2l16(const unsigned short* g, unsigned short* l) {
  __builtin_amdgcn_global_load_lds(
      (const __attribute__((address_space(1))) unsigned int*)g,
      (__attribute__((address_space(3))) unsigned int*)l, 16, 0, 0);
}

// ---------------------------------------------------------------- GEMM ----
// C = A(MxK bf16) @ W(NxK bf16)^T. Counted-vmcnt dbuf, XOR-swz LDS,
// bijective m-fastest XCD remap.
// EPI: 0=+bias, 1=+bias+gelu, 2=res+gate*(v+bias),
//   3=EPI2 + per-row {sum,sumsq} slot write, 4=LN-fold apply, 5=EPI4+gelu.
// Config law (R7, R14 both confirmed): keep >=2 blocks/CU — inter-block TLP
// hides the vmcnt stall; BK=128 at 144KB LDS (1 blk/CU) regressed +476us.
template <int BM, int BN, int BK, int EPI>
__global__ __launch_bounds__(256) void gemm_v7(
    const unsigned short* __restrict__ A, int lda,
    const unsigned short* __restrict__ W, int ldw,
    const float* __restrict__ bias,
    float* __restrict__ Cf, unsigned short* __restrict__ Cb, int ldc,
    const float* __restrict__ res, const float* __restrict__ gate,
    float* __restrict__ stats,
    int M, int N, int K)
{
  __shared__ unsigned short As[2][BM * BK];
  __shared__ unsigned short Bs[2][BN * BK];
  constexpr int FM = BM / 32, FN = BN / 32;
  constexpr int CPR = BK / 8;
  constexpr int LPS = (BM + BN) * BK / 2048;
  int m0, n0;
  {
    const int gx = gridDim.x;
    const int nwg = gx * gridDim.y;
    const int orig = blockIdx.y * gx + blockIdx.x;
    const int xcd = orig & 7, rem = orig >> 3;
    const int qq = nwg >> 3, rr = nwg & 7;
    const int wgid = (xcd < rr ? xcd * (qq + 1) : rr * (qq + 1) + (xcd - rr) * qq) + rem;
    m0 = (wgid % gx) * BM; n0 = (wgid / gx) * BN;
  }
  const int tid = threadIdx.x, lane = tid & 63, wid = tid >> 6;
  const int wr = wid >> 1, wc = wid & 1;
  const int fr = lane & 15, kq8 = lane >> 4;

  f32x4 acc[FM][FN];
#pragma unroll
  for (int mi = 0; mi < FM; ++mi)
#pragma unroll
    for (int ni = 0; ni < FN; ++ni) acc[mi][ni] = f32x4{0.f, 0.f, 0.f, 0.f};

  auto stage = [&](int buf, int k0) {
    const unsigned short* Ab = A + (size_t)m0 * lda + k0;
    const unsigned short* Bb = W + (size_t)n0 * ldw + k0;
#pragma unroll
    for (int ra = 0; ra < BM * BK / 2048; ++ra) {
      int c = ra * 256 + tid;
      int row = c / CPR, slot = c % CPR;
      g2l16(Ab + (size_t)row * lda + (slot ^ (row & 7)) * 8, &As[buf][c * 8]);
    }
#pragma unroll
    for (int rb = 0; rb < BN * BK / 2048; ++rb) {
      int c = rb * 256 + tid;
      int row = c / CPR, slot = c % CPR;
      g2l16(Bb + (size_t)row * ldw + (slot ^ (row & 7)) * 8, &Bs[buf][c * 8]);
    }
  };

  const int nt = K / BK;
  stage(0, 0);
  int cur = 0;
  for (int t = 0; t < nt; ++t) {
    if (t + 1 < nt) {
      stage(cur ^ 1, (t + 1) * BK);
      asm volatile("s_waitcnt vmcnt(%0)" :: "i"(LPS) : "memory");
    } else {
      asm volatile("s_waitcnt vmcnt(0)" ::: "memory");
    }
    __builtin_amdgcn_s_barrier();
#pragma unroll
    for (int ks = 0; ks < BK / 32; ++ks) {
      bf16x8 av[FM], bv[FN];
#pragma unroll
      for (int mi = 0; mi < FM; ++mi) {
        int row = wr * (BM / 2) + mi * 16 + fr;
        int idx = row * BK + (((ks * 4 + kq8) ^ (row & 7)) << 3);
        av[mi] = __builtin_bit_cast(bf16x8, *(const u16x8*)&As[cur][idx]);
      }
#pragma unroll
      for (int ni = 0; ni < FN; ++ni) {
        int row = wc * (BN / 2) + ni * 16 + fr;
        int idx = row * BK + (((ks * 4 + kq8) ^ (row & 7)) << 3);
        bv[ni] = __builtin_bit_cast(bf16x8, *(const u16x8*)&Bs[cur][idx]);
      }
#pragma unroll
      for (int mi = 0; mi < FM; ++mi)
#pragma unroll
        for (int ni = 0; ni < FN; ++ni)
          acc[mi][ni] = __builtin_amdgcn_mfma_f32_16x16x32_bf16(av[mi], bv[ni], acc[mi][ni], 0, 0, 0);
    }
    __builtin_amdgcn_s_barrier();
    cur ^= 1;
  }

  const int er = (lane >> 4) * 4, ec = lane & 15;
  float mu_[FM][4], rs_[FM][4];
  if constexpr (EPI >= 4) {
#pragma unroll
    for (int mi = 0; mi < FM; ++mi)
#pragma unroll
      for (int i = 0; i < 4; ++i) {
        int gr = m0 + wr * (BM / 2) + mi * 16 + er + i;
        float su = 0.f, sq = 0.f;
        if (gr < M) {
          const f32x4* sp = (const f32x4*)&stats[(size_t)gr * 48];
#pragma unroll
          for (int j = 0; j < 12; ++j) {
            f32x4 v4 = sp[j];
            su += v4.x + v4.z;
            sq += v4.y + v4.w;
          }
        }
        float mu = su * (1.0f / 768.0f);
        mu_[mi][i] = mu;
        rs_[mi][i] = rsqrtf(fmaxf(sq * (1.0f / 768.0f) - mu * mu, 0.f) + 1e-6f);
      }
  }
  float ssum[FM][4], sqsum[FM][4];
  if constexpr (EPI == 3) {
#pragma unroll
    for (int mi = 0; mi < FM; ++mi)
#pragma unroll
      for (int i = 0; i < 4; ++i) { ssum[mi][i] = 0.f; sqsum[mi][i] = 0.f; }
  }
#pragma unroll
  for (int mi = 0; mi < FM; ++mi)
#pragma unroll
    for (int ni = 0; ni < FN; ++ni) {
      int gc = n0 + wc * (BN / 2) + ni * 16 + ec;
      float bi = bias ? bias[gc] : 0.0f;
      float gg = gate ? gate[gc] : 1.0f;
#pragma unroll
      for (int i = 0; i < 4; ++i) {
        int gr = m0 + wr * (BM / 2) + mi * 16 + er + i;
        float v = acc[mi][ni][i];
        if constexpr (EPI == 0) {
          v += bi;
        } else if constexpr (EPI == 1) {
          v += bi;
          v = v / (1.0f + __expf(-1.59576912f * (v + 0.044715f * v * v * v)));
        } else if constexpr (EPI == 2 || EPI == 3) {
          v += bi;
          if (gr < M) v = res[(size_t)gr * ldc + gc] + gg * v;
        } else {
          v = (v - mu_[mi][i] * gg) * rs_[mi][i] + bi;
          if constexpr (EPI == 5)
            v = v / (1.0f + __expf(-1.59576912f * (v + 0.044715f * v * v * v)));
        }
        if (gr < M) {
          if (Cf) Cf[(size_t)gr * ldc + gc] = v;
          if (Cb) Cb[(size_t)gr * ldc + gc] = f2bf(v);
        }
        if constexpr (EPI == 3) { ssum[mi][i] += v; sqsum[mi][i] += v * v; }
      }
    }
  if constexpr (EPI == 3) {
    const int nb = n0 >> 6;
#pragma unroll
    for (int mi = 0; mi < FM; ++mi)
#pragma unroll
      for (int i = 0; i < 4; ++i) {
        float s = ssum[mi][i], q = sqsum[mi][i];
#pragma unroll
        for (int off = 1; off <= 8; off <<= 1) {
          s += __shfl_xor(s, off);
          q += __shfl_xor(q, off);
        }
        int gr = m0 + wr * (BM / 2) + mi * 16 + er + i;
        if ((lane & 15) == 0 && gr < M) {
          stats[(size_t)gr * 48 + (nb * 2 + wc) * 2]     = s;
          stats[(size_t)gr * 48 + (nb * 2 + wc) * 2 + 1] = q;
        }
      }
  }
}

// ------------------------------------------------------ MFMA attention ----
template <int LKPAD>
__global__ __launch_bounds__(256) void attn_mfma(
    const unsigned short* __restrict__ Q, int ldq, int qoff, int Lq,
    const unsigned short* __restrict__ KV, int ldkv, int koff, int voff, int Lk,
    const float* __restrict__ cq, const float* __restrict__ sq, int rbq,
    const float* __restrict__ ck, const float* __restrict__ sk, int rbk,
    unsigned short* __restrict__ Out)
{
  constexpr int NT = LKPAD / 16;
  constexpr int NKS = LKPAD / 32;
  __shared__ unsigned short Kb[LKPAD * 64];
  __shared__ unsigned short Vt[64 * LKPAD];
  __shared__ unsigned short Qs[4][16 * 64];
  __shared__ unsigned short Pl[4][16 * LKPAD];
  const int b = blockIdx.x / NH_, h = blockIdx.x - b * NH_;
  const int tid = threadIdx.x, lane = tid & 63, wid = tid >> 6;

  for (int idx = tid; idx < LKPAD * 32; idx += 256) {
    int t = idx >> 5, m = idx & 31;
    int d = 2 * m;
    int ksl = (t << 6) + (((m >> 2) ^ (t & 7)) << 3) + ((m & 3) << 1);
    int vs0 = d * LKPAD + (((t >> 3) ^ (d & 7)) << 3) + (t & 7);
    int vs1 = (d + 1) * LKPAD + (((t >> 3) ^ ((d + 1) & 7)) << 3) + (t & 7);
    if (t < Lk) {
      size_t rowb = ((size_t)b * Lk + t) * ldkv;
      unsigned int kw = *(const unsigned int*)(KV + rowb + koff + h * DH_ + d);
      unsigned int vw = *(const unsigned int*)(KV + rowb + voff + h * DH_ + d);
      float k1 = bflo(kw), k2 = bfhi(kw);
      size_t ri = (size_t)b * rbk + (size_t)t * 32 + m;
      float c = ck[ri], s = sk[ri];
      *(unsigned int*)&Kb[ksl] = packbf2((k1 * c - k2 * s) * 0.125f, (k1 * s + k2 * c) * 0.125f);
      Vt[vs0] = (unsigned short)(vw & 0xffff);
      Vt[vs1] = (unsigned short)(vw >> 16);
    } else {
      *(unsigned int*)&Kb[ksl] = 0;
      Vt[vs0] = 0; Vt[vs1] = 0;
    }
  }
  const int qbase = blockIdx.y * 64 + wid * 16;
  for (int idx = lane; idx < 16 * 32; idx += 64) {
    int r = idx >> 5, m = idx & 31;
    int gq = qbase + r;
    unsigned int qr = 0;
    if (gq < Lq) {
      unsigned int qw = *(const unsigned int*)(Q + ((size_t)b * Lq + gq) * ldq + qoff + h * DH_ + 2 * m);
      float q1 = bflo(qw), q2 = bfhi(qw);
      size_t ri = (size_t)b * rbq + (size_t)gq * 32 + m;
      float c = cq[ri], s = sq[ri];
      qr = packbf2(q1 * c - q2 * s, q1 * s + q2 * c);
    }
    *(unsigned int*)&Qs[wid][(r << 6) + (((m >> 2) ^ (r & 7)) << 3) + ((m & 3) << 1)] = qr;
  }
  __syncthreads();

  const int fr = lane & 15, g = lane >> 4;
  bf16x8 qa[2];
#pragma unroll
  for (int ks = 0; ks < 2; ++ks)
    qa[ks] = __builtin_bit_cast(bf16x8,
        *(const u16x8*)&Qs[wid][(fr << 6) + ((((ks << 2) + g) ^ (fr & 7)) << 3)]);

  f32x4 sv[NT];
  __builtin_amdgcn_s_setprio(1);
#pragma unroll
  for (int t = 0; t < NT; ++t) {
    int key = (t << 4) + fr;
    f32x4 a = {0.f, 0.f, 0.f, 0.f};
#pragma unroll
    for (int ks = 0; ks < 2; ++ks) {
      bf16x8 kb = __builtin_bit_cast(bf16x8,
          *(const u16x8*)&Kb[(key << 6) + ((((ks << 2) + g) ^ (key & 7)) << 3)]);
      a = __builtin_amdgcn_mfma_f32_16x16x32_bf16(qa[ks], kb, a, 0, 0, 0);
    }
    sv[t] = a;
  }
  __builtin_amdgcn_s_setprio(0);
#pragma unroll
  for (int t = 0; t < NT; ++t) {
    int key = (t << 4) + fr;
    if (key >= Lk) sv[t] = f32x4{-1e30f, -1e30f, -1e30f, -1e30f};
  }
  f32x4 mx = sv[0];
#pragma unroll
  for (int t = 1; t < NT; ++t)
#pragma unroll
    for (int i = 0; i < 4; ++i) mx[i] = fmaxf(mx[i], sv[t][i]);
#pragma unroll
  for (int off = 1; off <= 8; off <<= 1)
#pragma unroll
    for (int i = 0; i < 4; ++i) mx[i] = fmaxf(mx[i], __shfl_xor(mx[i], off));
  f32x4 sm = {0.f, 0.f, 0.f, 0.f};
#pragma unroll
  for (int t = 0; t < NT; ++t)
#pragma unroll
    for (int i = 0; i < 4; ++i) {
      float e = __expf(sv[t][i] - mx[i]);
      sv[t][i] = e;
      sm[i] += e;
    }
#pragma unroll
  for (int off = 1; off <= 8; off <<= 1)
#pragma unroll
    for (int i = 0; i < 4; ++i) sm[i] += __shfl_xor(sm[i], off);
  f32x4 inv;
#pragma unroll
  for (int i = 0; i < 4; ++i) inv[i] = 1.0f / sm[i];
#pragma unroll
  for (int t = 0; t < NT; ++t) {
    int key = (t << 4) + fr;
    int chunk = key >> 3;
#pragma unroll
    for (int i = 0; i < 4; ++i) {
      int row = (g << 2) + i;
      Pl[wid][row * LKPAD + ((chunk ^ (row & 7)) << 3) + (key & 7)] = f2bf(sv[t][i]);
    }
  }
  f32x4 oacc[4];
#pragma unroll
  for (int n = 0; n < 4; ++n) oacc[n] = f32x4{0.f, 0.f, 0.f, 0.f};
  __builtin_amdgcn_s_setprio(1);
#pragma unroll
  for (int ks = 0; ks < NKS; ++ks) {
    int chunk = (ks << 2) + g;
    bf16x8 pa = __builtin_bit_cast(bf16x8,
        *(const u16x8*)&Pl[wid][fr * LKPAD + ((chunk ^ (fr & 7)) << 3)]);
#pragma unroll
    for (int n = 0; n < 4; ++n) {
      int drow = (n << 4) + fr;
      bf16x8 vb = __builtin_bit_cast(bf16x8,
          *(const u16x8*)&Vt[drow * LKPAD + ((chunk ^ (drow & 7)) << 3)]);
      oacc[n] = __builtin_amdgcn_mfma_f32_16x16x32_bf16(pa, vb, oacc[n], 0, 0, 0);
    }
  }
  __builtin_amdgcn_s_setprio(0);
#pragma unroll
  for (int n = 0; n < 4; ++n)
#pragma unroll
    for (int i = 0; i < 4; ++i) {
      int gq = qbase + (g << 2) + i;
      if (gq < Lq)
        Out[((size_t)b * Lq + gq) * D_ + h * DH_ + (n << 4) + fr] = f2bf(oacc[n][i] * inv[i]);
    }
}

// ------------------------------------------------------ weight convert ----
struct CvtA {
  const float* s[11];
  unsigned short* d[11];
  const float* g[11];
  unsigned int lsrc[11];
  unsigned int lstride[11];
  int blkEnd[11];
};
__global__ __launch_bounds__(256) void cvt_multi_k(CvtA c) {
  int bid = blockIdx.x;
  int seg = 0;
#pragma unroll
  for (int i = 0; i < 10; ++i) seg += (bid >= c.blkEnd[i]) ? 1 : 0;
  unsigned int e = (unsigned int)(bid - (seg ? c.blkEnd[seg - 1] : 0)) * 2048u
                   + (unsigned int)threadIdx.x * 8u;
  unsigned int l = e / c.lsrc[seg], r = e - l * c.lsrc[seg];
  const float* s = c.s[seg] + e;
  unsigned short* d = c.d[seg] + (size_t)l * c.lstride[seg] + r;
  f32x4 a = *(const f32x4*)s, b2 = *(const f32x4*)(s + 4);
  const float* gp = c.g[seg];
  if (gp) {
    unsigned int k = e % 768u;
    const float* gpp = gp + (size_t)l * 768u + k;
    f32x4 ga = *(const f32x4*)gpp, gb = *(const f32x4*)(gpp + 4);
    a.x *= ga.x; a.y *= ga.y; a.z *= ga.z; a.w *= ga.w;
    b2.x *= gb.x; b2.y *= gb.y; b2.z *= gb.z; b2.w *= gb.w;
  }
  u16x8 o;
  o[0] = f2bf(a.x); o[1] = f2bf(a.y); o[2] = f2bf(a.z); o[3] = f2bf(a.w);
  o[4] = f2bf(b2.x); o[5] = f2bf(b2.y); o[6] = f2bf(b2.z); o[7] = f2bf(b2.w);
  *(u16x8*)d = o;
}

// LN-fold vectors: c_n = sum_k gamma_k W[n,k]; b_n = bias_n + sum_k beta_k W[n,k]
__global__ __launch_bounds__(256) void foldprep_k(
    const float* __restrict__ qkvw, const float* __restrict__ qkvb,
    const float* __restrict__ g1, const float* __restrict__ b1,
    const float* __restrict__ m1w, const float* __restrict__ m1b,
    const float* __restrict__ g2, const float* __restrict__ b2,
    float* __restrict__ cq, float* __restrict__ bq,
    float* __restrict__ cm, float* __restrict__ bm)
{
  int row = blockIdx.x * 4 + (threadIdx.x >> 6);
  int lane = threadIdx.x & 63;
  const int QT = L_ * 2304;
  const float *wrow, *gv, *bv;
  float bb; float *co, *bo; int oi;
  if (row < QT) {
    int l = row / 2304, n = row - l * 2304;
    wrow = qkvw + ((size_t)l * 2304 + n) * 768;
    gv = g1 + l * 768; bv = b1 + l * 768;
    bb = qkvb[row]; co = cq; bo = bq; oi = row;
  } else {
    int r2 = row - QT;
    int l = r2 / 3072, n = r2 - l * 3072;
    wrow = m1w + ((size_t)l * 3072 + n) * 768;
    gv = g2 + l * 768; bv = b2 + l * 768;
    bb = m1b[r2]; co = cm; bo = bm; oi = r2;
  }
  float cs = 0.f, bs = 0.f;
#pragma unroll
  for (int j = 0; j < 12; ++j) {
    float w = wrow[lane + 64 * j];
    cs += w * gv[lane + 64 * j];
    bs += w * bv[lane + 64 * j];
  }
  for (int o = 32; o; o >>= 1) { cs += __shfl_xor(cs, o); bs += __shfl_xor(bs, o); }
  if (lane == 0) { co[oi] = cs; bo[oi] = bb + bs; }
}

__global__ void cvt_patch_k(const float* __restrict__ s, unsigned short* __restrict__ d) {
  int i = blockIdx.x * 256 + threadIdx.x;
  if (i >= 768 * 768) return;
  int r = i / 768, col = i - r * 768;
  d[i] = f2bf(col < 588 ? s[r * 588 + col] : 0.0f);
}

// merged: scene rope table + fused biases (fb, fb2)
__global__ void prep_misc_k(float* __restrict__ c, float* __restrict__ s,
                            const float* __restrict__ wqb, const float* __restrict__ rkvb,
                            const float* __restrict__ wkvb, const float* __restrict__ rqb,
                            float* __restrict__ fb, float* __restrict__ fb2) {
  int idx = blockIdx.x * 256 + threadIdx.x;
  if (idx < S_ * 32) {
    int t = idx >> 5, m = idx & 31;
    int i = t >> 4, j = t & 15;
    float xx = -1.0f + 2.0f * j / 15.0f;
    float yy = -1.0f + 2.0f * i / 15.0f;
    float coord = (m < 16) ? xx : yy;
    float per = powf(100.0f, (float)(m & 15) / 16.0f);
    float ang = coord / per;
    c[idx] = cosf(ang); s[idx] = sinf(ang);
  }
  if (idx < L_ * 2304) {
    int l = idx / 2304, cc = idx - l * 2304;
    fb[idx]  = (cc < 768) ? wqb[l * 768 + cc] : rkvb[l * 1536 + (cc - 768)];
    fb2[idx] = (cc < 1536) ? wkvb[l * 1536 + cc] : rqb[((l + 1) % L_) * 768 + (cc - 1536)];
  }
}

// --------------------------------------------------------------- misc ----
__global__ void init_scene_k(const float* __restrict__ tok, float* __restrict__ sf,
                             unsigned short* __restrict__ sb, int total) {
  int i = blockIdx.x * 256 + threadIdx.x;
  if (i < total) {
    float v = tok[i % (S_ * D_)];
    sf[i] = v; sb[i] = f2bf(v);
  }
}

// im2col + local rope table in one kernel
__global__ void im2col_k(unsigned short* __restrict__ xb, const float* __restrict__ img,
                         const float* __restrict__ ctr, const float* __restrict__ scl,
                         float* __restrict__ lc, float* __restrict__ ls) {
  int idx = blockIdx.x * 256 + threadIdx.x;
  if (idx >= 784 * 768) return;
  int row = idx / 768, col = idx - row * 768;
  float val = 0.0f;
  if (col < 588) {
    int b = row / 49, pch = row - b * 49;
    int c = col / 196, rr = col - c * 196;
    int i = rr / 14, j = rr - i * 14;
    int py = pch / 7, px = pch - py * 7;
    int gyi = py * 14 + i, gxi = px * 14 + j;
    float cx = ctr[b * 2], cy = ctr[b * 2 + 1], sc = scl[b];
    float gy = cy + sc * (-1.0f + 2.0f * gyi / 97.0f);
    float gx = cx + sc * (-1.0f + 2.0f * gxi / 97.0f);
    float pyi = (gy + 1.0f) * 0.5f * 223.0f;
    float pxi = (gx + 1.0f) * 0.5f * 223.0f;
    float y0f = fminf(fmaxf(floorf(pyi), 0.0f), 222.0f);
    float x0f = fminf(fmaxf(floorf(pxi), 0.0f), 222.0f);
    int y0 = (int)y0f, x0 = (int)x0f;
    float wy = fminf(fmaxf(pyi - y0f, 0.0f), 1.0f);
    float wx = fminf(fmaxf(pxi - x0f, 0.0f), 1.0f);
    const float* base = img + (size_t)(b * 3 + c) * 224 * 224;
    float v00 = base[y0 * 224 + x0],       v01 = base[y0 * 224 + x0 + 1];
    float v10 = base[(y0 + 1) * 224 + x0], v11 = base[(y0 + 1) * 224 + x0 + 1];
    val = (v00 * (1.0f - wy) + v10 * wy) * (1.0f - wx) + (v01 * (1.0f - wy) + v11 * wy) * wx;
  }
  xb[idx] = f2bf(val);
  if (idx < B_ * N_ * 32) {
    int b = idx / (N_ * 32);
    int r = idx - b * (N_ * 32);
    int pch = r >> 5, m = r & 31;
    int py = pch / 7, px = pch - py * 7;
    float cx = ctr[b * 2], cy = ctr[b * 2 + 1], sc = scl[b];
    float gx = cx + sc * ((px - 3.0f) / 3.0f);
    float gy = cy + sc * ((py - 3.0f) / 3.0f);
    float coord = (m < 16) ? gx : gy;
    float per = powf(100.0f, (float)(m & 15) / 16.0f);
    float ang = coord / per;
    lc[idx] = cosf(ang); ls[idx] = sinf(ang);
  }
}

// -------------------------------------------------------------- launch ----
extern "C" void kernel_launch(void* const* d_in, const int* in_sizes, int n_in,
                              void* d_out, int out_size, void* d_ws, size_t ws_size,
                              hipStream_t stream) {
  const float* images    = (const float*)d_in[0];
  const float* centers   = (const float*)d_in[1];
  const float* scales    = (const float*)d_in[2];
  const float* patch_w   = (const float*)d_in[3];
  const float* patch_b   = (const float*)d_in[4];
  const float* scene_tok = (const float*)d_in[5];
  const float* ln1_w = (const float*)d_in[6];
  const float* ln1_b = (const float*)d_in[7];
  const float* ln2_w = (const float*)d_in[8];
  const float* ln2_b = (const float*)d_in[9];
  const float* qkv_w = (const float*)d_in[10];
  const float* qkv_b = (const float*)d_in[11];
  const float* ao_w  = (const float*)d_in[12];
  const float* ao_b  = (const float*)d_in[13];
  const float* m1_w  = (const float*)d_in[14];
  const float* m1_b  = (const float*)d_in[15];
  const float* m2_w  = (const float*)d_in[16];
  const float* m2_b  = (const float*)d_in[17];
  const float* rq_w  = (const float*)d_in[18];
  const float* rq_b  = (const float*)d_in[19];
  const float* rkv_w = (const float*)d_in[20];
  const float* rkv_b = (const float*)d_in[21];
  const float* ro_w  = (const float*)d_in[22];
  const float* ro_b  = (const float*)d_in[23];
  const float* rgate = (const float*)d_in[24];
  const float* wq_w  = (const float*)d_in[25];
  const float* wq_b  = (const float*)d_in[26];
  const float* wkv_w = (const float*)d_in[27];
  const float* wkv_b = (const float*)d_in[28];
  const float* wo_w  = (const float*)d_in[29];
  const float* wo_b  = (const float*)d_in[30];
  const float* wgate = (const float*)d_in[31];

  float* scene_f = (float*)d_out;

  char* p = (char*)d_ws;
  auto alloc = [&](size_t bytes) { char* r = p; p += (bytes + 255) & ~(size_t)255; return (void*)r; };
  unsigned short* scene_bf = (unsigned short*)alloc((size_t)4096 * 768 * 2);
  float*          local_f  = (float*)alloc((size_t)784 * 768 * 4);
  unsigned short* local_bf = (unsigned short*)alloc((size_t)896 * 768 * 2);
  unsigned short* q_r_bf   = (unsigned short*)alloc((size_t)896 * 768 * 2);
  unsigned short* qrkv_bf  = (unsigned short*)alloc((size_t)4096 * 2304 * 2);
  unsigned short* kv_bf    = (unsigned short*)alloc((size_t)896 * 2304 * 2);
  unsigned short* kvq_bf   = (unsigned short*)alloc((size_t)896 * 2304 * 2);
  unsigned short* act_bf   = (unsigned short*)alloc((size_t)4096 * 768 * 2);
  unsigned short* x_bf     = (unsigned short*)alloc((size_t)896 * 768 * 2);
  float* sc_cos = (float*)alloc((size_t)S_ * 32 * 4);
  float* sc_sin = (float*)alloc((size_t)S_ * 32 * 4);
  float* l_cos  = (float*)alloc((size_t)B_ * N_ * 32 * 4);
  float* l_sin  = (float*)alloc((size_t)B_ * N_ * 32 * 4);
  unsigned short* patch_wbf = (unsigned short*)alloc((size_t)768 * 768 * 2);
  float*          fb        = (float*)alloc((size_t)L_ * 2304 * 4);
  float*          fb2       = (float*)alloc((size_t)L_ * 2304 * 4);
  float*          cq_v      = (float*)alloc((size_t)L_ * 2304 * 4);
  float*          bq_v      = (float*)alloc((size_t)L_ * 2304 * 4);
  float*          cm_v      = (float*)alloc((size_t)L_ * 3072 * 4);
  float*          bm_v      = (float*)alloc((size_t)L_ * 3072 * 4);
  float*          stats1    = (float*)alloc((size_t)832 * 48 * 4);
  float*          stats2    = (float*)alloc((size_t)832 * 48 * 4);

  static const size_t REGSZ[9] = {589824, 1769472, 589824, 1769472, 589824,
                                  2359296, 2359296, 1769472, 589824};
  struct SegDef { const float* src; int reg; unsigned off; unsigned lsrc; int nl; const float* gma; };
  const SegDef SEGS[11] = {
    {rq_w,            0, 0,       589824,  L_,     nullptr},
    {wq_w,            1, 0,       589824,  L_,     nullptr},
    {rkv_w,           1, 589824,  1179648, L_,     nullptr},
    {ro_w,            2, 0,       589824,  L_,     nullptr},
    {qkv_w,           3, 0,       1769472, L_,     ln1_w},
    {ao_w,            4, 0,       589824,  L_,     nullptr},
    {m1_w,            5, 0,       2359296, L_,     ln2_w},
    {m2_w,            6, 0,       2359296, L_,     nullptr},
    {wkv_w,           7, 0,       1179648, L_,     nullptr},
    {rq_w + 589824,   7, 1179648, 589824,  L_ - 1, nullptr},
    {wo_w,            8, 0,       589824,  L_,     nullptr},
  };
  size_t regBase[9];
  size_t perLayer = 0;
  {
    size_t cur = 0;
    for (int i = 0; i < 9; ++i) { regBase[i] = cur; cur += REGSZ[i] * L_; perLayer += REGSZ[i]; }
  }
  const size_t allElems = perLayer * L_;
  size_t usedBytes = (size_t)(p - (char*)d_ws);
  bool preconv = ws_size >= usedBytes + allElems * 2 + 4096;
  unsigned short* wbf = (unsigned short*)alloc((preconv ? allElems : perLayer) * 2);

  {
    int total = B_ * S_ * D_;
    init_scene_k<<<(total + 255) / 256, 256, 0, stream>>>(scene_tok, scene_f, scene_bf, total);
    prep_misc_k<<<(L_ * 2304 + 255) / 256, 256, 0, stream>>>(
        sc_cos, sc_sin, wq_b, rkv_b, wkv_b, rq_b, fb, fb2);
    cvt_patch_k<<<(768 * 768 + 255) / 256, 256, 0, stream>>>(patch_w, patch_wbf);
    foldprep_k<<<(L_ * (2304 + 3072)) / 4, 256, 0, stream>>>(
        qkv_w, qkv_b, ln1_w, ln1_b, m1_w, m1_b, ln2_w, ln2_b, cq_v, bq_v, cm_v, bm_v);
    if (preconv) {
      CvtA cv;
      int blk = 0;
      for (int i = 0; i < 11; ++i) {
        cv.s[i] = SEGS[i].src;
        cv.d[i] = wbf + regBase[SEGS[i].reg] + SEGS[i].off;
        cv.g[i] = SEGS[i].gma;
        cv.lsrc[i] = SEGS[i].lsrc;
        cv.lstride[i] = (unsigned)REGSZ[SEGS[i].reg];
        blk += (int)((size_t)SEGS[i].lsrc * SEGS[i].nl / 2048);
        cv.blkEnd[i] = blk;
      }
      cvt_multi_k<<<blk, 256, 0, stream>>>(cv);
    }
  }

  for (int vp = 0; vp < V_; ++vp) {
    const float* ctr = centers + (size_t)vp * B_ * 2;
    const float* scl = scales + (size_t)vp * B_;
    im2col_k<<<(784 * 768 + 255) / 256, 256, 0, stream>>>(x_bf, images, ctr, scl, l_cos, l_sin);
    gemm_v7<64, 64, 128, 0><<<dim3(13, 12), 256, 0, stream>>>(
        x_bf, 768, patch_wbf, 768, patch_b, local_f, local_bf, 768,
        nullptr, nullptr, nullptr, 784, 768, 768);

    for (int l = 0; l < L_; ++l) {
      const unsigned short* wR[9];
      if (preconv) {
        for (int rg = 0; rg < 9; ++rg)
          wR[rg] = wbf + regBase[rg] + (size_t)l * REGSZ[rg];
      } else {
        CvtA cv;
        int blk = 0;
        size_t cur = 0;
        size_t rb[9];
        for (int rg = 0; rg < 9; ++rg) { rb[rg] = cur; cur += REGSZ[rg]; wR[rg] = wbf + rb[rg]; }
        for (int i = 0; i < 11; ++i) {
          size_t srcl = (i == 9) ? (size_t)((l + 1) % L_) : (size_t)l;
          cv.s[i] = (i == 9 ? rq_w : SEGS[i].src) + srcl * SEGS[i].lsrc;
          cv.d[i] = wbf + rb[SEGS[i].reg] + SEGS[i].off;
          cv.g[i] = SEGS[i].gma ? SEGS[i].gma + srcl * 768 : nullptr;
          cv.lsrc[i] = SEGS[i].lsrc;
          cv.lstride[i] = (unsigned)REGSZ[SEGS[i].reg];
          blk += (int)(SEGS[i].lsrc / 2048);
          cv.blkEnd[i] = blk;
        }
        cvt_multi_k<<<blk, 256, 0, stream>>>(cv);
      }

      // ---- qrkv (scene): wq|rkv fused (<128,128,64>, 2 blk/CU) ----
      gemm_v7<128, 128, 64, 0><<<dim3(32, 18), 256, 0, stream>>>(
          scene_bf, 768, wR[1], 768, fb + (size_t)l * 2304,
          nullptr, qrkv_bf, 2304, nullptr, nullptr, nullptr, 4096, 2304, 768);
      if (l == 0)
        gemm_v7<64, 64, 128, 0><<<dim3(13, 12), 256, 0, stream>>>(
            local_bf, 768, wR[0], 768, rq_b + l * 768,
            nullptr, q_r_bf, 768, nullptr, nullptr, nullptr, 784, 768, 768);
      // ---- read cross ----
      if (l == 0)
        attn_mfma<256><<<dim3(B_ * NH_, 1), 256, 0, stream>>>(q_r_bf, 768, 0, 49,
            qrkv_bf, 2304, 768, 1536, 256, l_cos, l_sin, N_ * 32, sc_cos, sc_sin, 0, act_bf);
      else
        attn_mfma<256><<<dim3(B_ * NH_, 1), 256, 0, stream>>>(kvq_bf, 2304, 1536, 49,
            qrkv_bf, 2304, 768, 1536, 256, l_cos, l_sin, N_ * 32, sc_cos, sc_sin, 0, act_bf);
      // ro: residual + ln1 stats (slots)
      gemm_v7<64, 64, 128, 3><<<dim3(13, 12), 256, 0, stream>>>(
          act_bf, 768, wR[2], 768, ro_b + l * 768,
          local_f, local_bf, 768, local_f, rgate + l * 768, stats1, 784, 768, 768);
      // qkv: LN1 folded
      gemm_v7<64, 64, 128, 4><<<dim3(13, 36), 256, 0, stream>>>(
          local_bf, 768, wR[3], 768, bq_v + (size_t)l * 2304,
          nullptr, kv_bf, 2304, nullptr, cq_v + (size_t)l * 2304, stats1, 784, 2304, 768);
      attn_mfma<64><<<dim3(B_ * NH_, 1), 256, 0, stream>>>(kv_bf, 2304, 0, 49,
          kv_bf, 2304, 768, 1536, 49, l_cos, l_sin, N_ * 32, l_cos, l_sin, N_ * 32, act_bf);
      // ao: residual + ln2 stats
      gemm_v7<64, 64, 128, 3><<<dim3(13, 12), 256, 0, stream>>>(
          act_bf, 768, wR[4], 768, ao_b + l * 768,
          local_f, local_bf, 768, local_f, nullptr, stats2, 784, 768, 768);
      // m1: LN2 folded + gelu
      gemm_v7<64, 64, 128, 5><<<dim3(13, 48), 256, 0, stream>>>(
          local_bf, 768, wR[5], 768, bm_v + (size_t)l * 3072,
          nullptr, act_bf, 3072, nullptr, cm_v + (size_t)l * 3072, stats2, 784, 3072, 768);
      gemm_v7<64, 64, 128, 2><<<dim3(13, 12), 256, 0, stream>>>(
          act_bf, 3072, wR[6], 3072, m2_b + l * 768,
          local_f, local_bf, 768, local_f, nullptr, nullptr, 784, 768, 3072);
      // ---- wkv + rq(l+1) merged ----
      gemm_v7<64, 64, 128, 0><<<dim3(13, 36), 256, 0, stream>>>(
          local_bf, 768, wR[7], 768, fb2 + (size_t)l * 2304,
          nullptr, kvq_bf, 2304, nullptr, nullptr, nullptr, 784, 2304, 768);
      // ---- write cross ----
      attn_mfma<64><<<dim3(B_ * NH_, 4), 256, 0, stream>>>(qrkv_bf, 2304, 0, 256,
          kvq_bf, 2304, 0, 768, 49, sc_cos, sc_sin, 0, l_cos, l_sin, N_ * 32, act_bf);
      gemm_v7<128, 64, 64, 2><<<dim3(32, 12), 256, 0, stream>>>(
          act_bf, 768, wR[8], 768, wo_b + l * 768,
          scene_f, scene_bf, 768, scene_f, wgate + l * 768, nullptr, 4096, 768, 768);
    }
  }
}